// Round 6
// baseline (161.221 us; speedup 1.0000x reference)
//
#include <hip/hip_runtime.h>
#include <hip/hip_bf16.h>

// Problem: B=8, N=1024, DQ=DK=DV=256, H=8, head_dim=32.
// Pipeline (all bf16 MFMA, fp32 accum):
//   K0 wtrans : W[k][n] f32 -> WT[n][k] bf16 (LDS tile transpose, coalesced both ways)
//   K1 proj   : y=0: q=(Q@Wq+bq)*mask ; y=1: k AND v from one pass over K.
//               A tile staged once per block in LDS bf16; k pre-scaled by 1/sqrt(DV).
//               q,k: [b][h][n][32] ; v: [b][h][32][n] (transposed)
//   K2 attn   : 128 q-rows/block (grid 8 x 64); 4 waves x two 16-row sub-tiles share
//               each 64-key K/V chunk via double-buffered LDS (K/V read once per block;
//               half the L2 traffic of the 64-row version; stage+barrier amortized 2x).
//               Next-chunk loads issued before the barrier; per-sub-tile P buffers.
//   K3 fused  : 32 rows/block (grid 256): LN0 -> Xs (LDS bf16); GEMM x@Wo with each
//               weight fragment feeding 2 row-halves; y = x + relu(.); out = LN1(y).

typedef __attribute__((ext_vector_type(8))) short short8;
typedef __attribute__((ext_vector_type(4))) short short4v;
typedef __attribute__((ext_vector_type(4))) float f32x4;

__device__ __forceinline__ short f2bf(float f) {
    union { float f; unsigned u; } x; x.f = f;
    unsigned r = x.u + 0x7fffu + ((x.u >> 16) & 1u);   // RNE
    return (short)(r >> 16);
}
__device__ __forceinline__ float bf2f(short s) {
    union { unsigned u; float f; } x; x.u = ((unsigned)(unsigned short)s) << 16;
    return x.f;
}

// ---------------- K0: transpose + convert weights (coalesced via LDS) ----------------
__global__ __launch_bounds__(256) void wtrans_kernel(
    const float* __restrict__ Wq, const float* __restrict__ Wk,
    const float* __restrict__ Wv, const float* __restrict__ Wo,
    short* __restrict__ WqT, short* __restrict__ WkT,
    short* __restrict__ WvT, short* __restrict__ WoT)
{
    __shared__ short tile[64][72];                 // +8 pad: breaks pow2 stride
    const float* W; short* T;
    switch (blockIdx.y) {
        case 0:  W = Wq; T = WqT; break;
        case 1:  W = Wk; T = WkT; break;
        case 2:  W = Wv; T = WvT; break;
        default: W = Wo; T = WoT; break;
    }
    const int k0 = (blockIdx.x >> 2) * 64;         // source row tile
    const int n0 = (blockIdx.x & 3) * 64;          // source col tile
    const int c  = threadIdx.x & 63;
    const int r4 = threadIdx.x >> 6;
    #pragma unroll
    for (int i = 0; i < 16; i++) {
        int k = r4 + i * 4;
        tile[k][c] = f2bf(W[(size_t)(k0 + k) * 256 + n0 + c]);   // coalesced read
    }
    __syncthreads();
    #pragma unroll
    for (int i = 0; i < 16; i++) {
        int n = r4 + i * 4;
        T[(size_t)(n0 + n) * 256 + k0 + c] = tile[c][n];         // coalesced write
    }
}

// ---------------- K1: projections ----------------
// grid (256, 2) blocks of 256. Block: 32 token rows x 256 cols.
// y=0: q only. y=1: k AND v (one A pass, two MFMA chains). A tile staged in LDS.
__global__ __launch_bounds__(256) void proj_kernel(
    const float* __restrict__ Q, const float* __restrict__ Kin,
    const short* __restrict__ WqT, const short* __restrict__ WkT, const short* __restrict__ WvT,
    const float* __restrict__ bq, const float* __restrict__ bk, const float* __restrict__ bv,
    const int* __restrict__ lengths,
    short* __restrict__ qb, short* __restrict__ kb, short* __restrict__ vT)
{
    __shared__ short Xt[32][264];                 // A tile bf16; stride 528B -> 2-way (free)
    const int which = blockIdx.y;                 // 0=q, 1=k+v
    const float* A   = (which == 0) ? Q   : Kin;
    const short* WTa = (which == 0) ? WqT : WkT;

    const int tid = threadIdx.x;
    const int b = blockIdx.x >> 5;                // batch (32 rows/block, 32 blocks/batch)
    const int len = lengths[b];
    const int r0b = blockIdx.x * 32;              // block's token row base (global)
    const int ntok0b = r0b & 1023;                // within-batch row base of block

    // ---- stage A tile: 32 rows x 256 cols, f32 -> bf16, coalesced, converted once ----
    if (ntok0b < len) {
        #pragma unroll
        for (int it = 0; it < 8; it++) {
            int e = tid + it * 256;               // 2048 float4 loads total
            int row = e >> 6, c4 = (e & 63) * 4;
            float4 f = *(const float4*)(A + (size_t)(r0b + row) * 256 + c4);
            short4v s4;
            s4[0] = f2bf(f.x); s4[1] = f2bf(f.y); s4[2] = f2bf(f.z); s4[3] = f2bf(f.w);
            *(short4v*)(&Xt[row][c4]) = s4;
        }
    }
    __syncthreads();

    const int lane = tid & 63, wid = tid >> 6;
    const int m = lane & 15, quad = lane >> 4;
    const int rh = wid >> 1, ch = wid & 1;
    const int c0 = ch * 128;                      // wave's column base
    const int ntok0 = ntok0b + rh * 16;           // wave's within-batch row base

    f32x4 accA[8], accB[8];
    #pragma unroll
    for (int t = 0; t < 8; t++) {
        accA[t] = (f32x4){0.f, 0.f, 0.f, 0.f};
        accB[t] = (f32x4){0.f, 0.f, 0.f, 0.f};
    }

    if (ntok0 < len) {                            // fully-masked wave tiles: skip GEMM
        for (int kk = 0; kk < 256; kk += 32) {
            short8 af = *(const short8*)(&Xt[rh * 16 + m][kk + quad * 8]);
            #pragma unroll
            for (int t = 0; t < 8; t++) {
                short8 bfa = *(const short8*)(WTa + (c0 + t * 16 + m) * 256 + kk + quad * 8);
                accA[t] = __builtin_amdgcn_mfma_f32_16x16x32_bf16(af, bfa, accA[t], 0, 0, 0);
            }
            if (which == 1) {
                #pragma unroll
                for (int t = 0; t < 8; t++) {
                    short8 bfb = *(const short8*)(WvT + (c0 + t * 16 + m) * 256 + kk + quad * 8);
                    accB[t] = __builtin_amdgcn_mfma_f32_16x16x32_bf16(af, bfb, accB[t], 0, 0, 0);
                }
            }
        }
    }

    const float KSCALE = 0.0625f;                  // 1/sqrt(256), folded into kb
    #pragma unroll
    for (int t = 0; t < 8; t++) {
        int n = c0 + t * 16 + m;                   // output column
        int h = n >> 5, i = n & 31;
        int bh = b * 8 + h;
        if (which == 0) {
            float bias = bq[n];
            #pragma unroll
            for (int reg = 0; reg < 4; reg++) {
                int ntok = ntok0 + quad * 4 + reg; // C layout: row = quad*4+reg
                float val = (ntok < len) ? (accA[t][reg] + bias) : 0.f;
                qb[((size_t)bh * 1024 + ntok) * 32 + i] = f2bf(val);
            }
        } else {
            float bk_ = bk[n];
            float bv_ = bv[n];
            #pragma unroll
            for (int reg = 0; reg < 4; reg++) {
                int ntok = ntok0 + quad * 4 + reg;
                bool ok = ntok < len;
                float vk = ok ? (accA[t][reg] + bk_) * KSCALE : 0.f;
                float vv = ok ? (accB[t][reg] + bv_) : 0.f;
                kb[((size_t)bh * 1024 + ntok) * 32 + i] = f2bf(vk);
                vT[(size_t)(bh * 32 + i) * 1024 + ntok] = f2bf(vv);
            }
        }
    }
}

// ---------------- K2: attention ----------------
// grid (8, 64): x = 128-row q-tile, y = b*8+h. Block 256 = 4 waves; wave wid owns
// q-rows [bx*128 + wid*32, +32) as two 16-row sub-tiles. All waves share each
// 64-key K/V chunk via double-buffered LDS (read once per block from L2).
// One barrier per chunk; next-chunk loads issued before the barrier.
__global__ __launch_bounds__(256) void attn_kernel(
    const short* __restrict__ qb, const short* __restrict__ kb, const short* __restrict__ vT,
    const int* __restrict__ lengths, float* __restrict__ O1)
{
    __shared__ short Kb[2][64][36];                // 9216 B  (row stride 18 dw: <=2-way)
    __shared__ short Vb[2][32][76];                // 9728 B  (row stride 38 dw: ~2-way)
    __shared__ short P[4][2][16][72];              // 18432 B (per-wave, per-sub-tile)
    const int tid = threadIdx.x;
    const int lane = tid & 63, wid = tid >> 6;
    const int m = lane & 15, quad = lane >> 4;
    const int bh = blockIdx.y;
    const int b = bh >> 3, h = bh & 7;
    const int len = lengths[b];
    const int qr0 = blockIdx.x * 128 + wid * 32;   // wave's first sub-tile row
    const bool act0 = qr0 < len;
    const bool act1 = qr0 + 16 < len;

    const short* qbase = qb + (size_t)bh * 1024 * 32;
    const short* kbase = kb + (size_t)bh * 1024 * 32;
    const short* vbase = vT + (size_t)bh * 32 * 1024;

    // A-frags of q for both sub-tiles (zero rows beyond len: proj zeroed them)
    const short8 qf0 = *(const short8*)(qbase + (qr0 + m) * 32 + quad * 8);
    const short8 qf1 = *(const short8*)(qbase + (qr0 + 16 + m) * 32 + quad * 8);

    f32x4 o00 = (f32x4){0.f,0.f,0.f,0.f}, o01 = (f32x4){0.f,0.f,0.f,0.f};  // sub0
    f32x4 o10 = (f32x4){0.f,0.f,0.f,0.f}, o11 = (f32x4){0.f,0.f,0.f,0.f};  // sub1
    float l0[4] = {0.f,0.f,0.f,0.f};
    float l1[4] = {0.f,0.f,0.f,0.f};

    // block-uniform chunk count (block skips entirely if its 128 rows are all masked)
    const int nch = (blockIdx.x * 128 < len) ? ((len + 63) >> 6) : 0;

    short8 kr, vr;
    if (nch > 0) {                                 // prologue loads for chunk 0
        kr = *(const short8*)(kbase + tid * 8);
        vr = *(const short8*)(vbase + (size_t)(tid >> 3) * 1024 + (tid & 7) * 8);
    }

    for (int ci = 0; ci < nch; ci++) {
        const int buf = ci & 1;
        // stage current chunk (regs -> LDS); K: row tid>>2, V: row tid>>3
        *(short8*)(&Kb[buf][tid >> 2][(tid & 3) * 8]) = kr;
        *(short8*)(&Vb[buf][tid >> 3][(tid & 7) * 8]) = vr;
        if (ci + 1 < nch) {                        // issue next chunk's loads now
            int k1 = (ci + 1) * 64;
            kr = *(const short8*)(kbase + k1 * 32 + tid * 8);
            vr = *(const short8*)(vbase + (size_t)(tid >> 3) * 1024 + k1 + (tid & 7) * 8);
        }
        __syncthreads();                           // staged chunk visible to all waves

        const int key0 = ci * 64;
        if (act0) {
            #pragma unroll
            for (int t = 0; t < 4; t++) {
                short8 kf = *(const short8*)(&Kb[buf][t * 16 + m][quad * 8]);
                f32x4 s = __builtin_amdgcn_mfma_f32_16x16x32_bf16(qf0, kf,
                            (f32x4){0.f, 0.f, 0.f, 0.f}, 0, 0, 0);
                int col = key0 + t * 16 + m;
                bool cm = col < len;
                #pragma unroll
                for (int reg = 0; reg < 4; reg++) {
                    float e = cm ? __expf(s[reg]) : 0.f;   // scale pre-folded into kb
                    l0[reg] += e;
                    P[wid][0][quad * 4 + reg][t * 16 + m] = f2bf(e);
                }
            }
            asm volatile("s_waitcnt lgkmcnt(0)" ::: "memory");
            #pragma unroll
            for (int c = 0; c < 2; c++) {
                short8 pf  = *(const short8*)(&P[wid][0][m][c * 32 + quad * 8]);
                short8 vf0 = *(const short8*)(&Vb[buf][m][c * 32 + quad * 8]);
                short8 vf1 = *(const short8*)(&Vb[buf][16 + m][c * 32 + quad * 8]);
                o00 = __builtin_amdgcn_mfma_f32_16x16x32_bf16(pf, vf0, o00, 0, 0, 0);
                o01 = __builtin_amdgcn_mfma_f32_16x16x32_bf16(pf, vf1, o01, 0, 0, 0);
            }
        }
        if (act1) {
            #pragma unroll
            for (int t = 0; t < 4; t++) {
                short8 kf = *(const short8*)(&Kb[buf][t * 16 + m][quad * 8]);
                f32x4 s = __builtin_amdgcn_mfma_f32_16x16x32_bf16(qf1, kf,
                            (f32x4){0.f, 0.f, 0.f, 0.f}, 0, 0, 0);
                int col = key0 + t * 16 + m;
                bool cm = col < len;
                #pragma unroll
                for (int reg = 0; reg < 4; reg++) {
                    float e = cm ? __expf(s[reg]) : 0.f;
                    l1[reg] += e;
                    P[wid][1][quad * 4 + reg][t * 16 + m] = f2bf(e);
                }
            }
            asm volatile("s_waitcnt lgkmcnt(0)" ::: "memory");
            #pragma unroll
            for (int c = 0; c < 2; c++) {
                short8 pf  = *(const short8*)(&P[wid][1][m][c * 32 + quad * 8]);
                short8 vf0 = *(const short8*)(&Vb[buf][m][c * 32 + quad * 8]);
                short8 vf1 = *(const short8*)(&Vb[buf][16 + m][c * 32 + quad * 8]);
                o10 = __builtin_amdgcn_mfma_f32_16x16x32_bf16(pf, vf0, o10, 0, 0, 0);
                o11 = __builtin_amdgcn_mfma_f32_16x16x32_bf16(pf, vf1, o11, 0, 0, 0);
            }
        }
    }

    // reduce rowsums across the 16 lanes of each quad group (both sub-tiles)
    #pragma unroll
    for (int reg = 0; reg < 4; reg++) {
        float s = l0[reg];
        s += __shfl_xor(s, 1); s += __shfl_xor(s, 2);
        s += __shfl_xor(s, 4); s += __shfl_xor(s, 8);
        l0[reg] = s;
        float u = l1[reg];
        u += __shfl_xor(u, 1); u += __shfl_xor(u, 2);
        u += __shfl_xor(u, 4); u += __shfl_xor(u, 8);
        l1[reg] = u;
    }

    // direct per-wave epilogue
    const int hbase = h * 32;
    #pragma unroll
    for (int reg = 0; reg < 4; reg++) {
        int qrow = qr0 + quad * 4 + reg;           // sub0 row
        float f = (qrow < len) ? 1.f / (l0[reg] + 1e-15f) : 0.f;
        size_t obase = ((size_t)(b * 1024 + qrow)) * 256 + hbase;
        float q0 = bf2f(qbase[qrow * 32 + m]);
        float q1 = bf2f(qbase[qrow * 32 + 16 + m]);
        O1[obase + m]      = q0 + o00[reg] * f;
        O1[obase + 16 + m] = q1 + o01[reg] * f;
    }
    #pragma unroll
    for (int reg = 0; reg < 4; reg++) {
        int qrow = qr0 + 16 + quad * 4 + reg;      // sub1 row
        float f = (qrow < len) ? 1.f / (l1[reg] + 1e-15f) : 0.f;
        size_t obase = ((size_t)(b * 1024 + qrow)) * 256 + hbase;
        float q0 = bf2f(qbase[qrow * 32 + m]);
        float q1 = bf2f(qbase[qrow * 32 + 16 + m]);
        O1[obase + m]      = q0 + o10[reg] * f;
        O1[obase + 16 + m] = q1 + o11[reg] * f;
    }
}

// ---------------- K3: fused LN0 + output projection + relu residual + LN1 ----------------
// grid 256 blocks of 256 (4 waves). Block: 32 token rows x full 256 cols.
// Phase 1: LN0 from O1 -> normalized bf16 x staged in LDS (8 threads/row x 32 cols).
// Phase 2: GEMM x@Wo from LDS; wave = 32 rows x 64 cols, each weight fragment
//          feeds two 16-row sub-tiles (2x in-register weight reuse, half the blocks
//          -> half the WoT L2 traffic vs the 16-row version).
// Phase 3: y = x + relu(c+bo); LN1 row stats across 4 col-quarter waves via LDS.
__global__ __launch_bounds__(256) void out_kernel(
    const float* __restrict__ O1, const short* __restrict__ WoT,
    const float* __restrict__ g0, const float* __restrict__ b0,
    const float* __restrict__ bo, const float* __restrict__ g1, const float* __restrict__ b1,
    float* __restrict__ out)
{
    __shared__ short Xs[32][264];                  // normalized x, bf16, padded stride
    __shared__ float st[4][2][32];                 // [wave][{s1,s2}][row]
    const int tid = threadIdx.x;
    const int r0 = blockIdx.x * 32;

    // ---- Phase 1: LN0. 8 threads per row, 32 cols per thread. ----
    {
        const int lrow  = tid >> 3;                // 0..31
        const int cbase = (tid & 7) * 32;
        const float* rowp = O1 + (size_t)(r0 + lrow) * 256 + cbase;
        float4 a[8];
        #pragma unroll
        for (int j = 0; j < 8; j++) a[j] = ((const float4*)rowp)[j];
        float s = 0.f, s2 = 0.f;
        #pragma unroll
        for (int j = 0; j < 8; j++) {
            s  += a[j].x + a[j].y + a[j].z + a[j].w;
            s2 += a[j].x*a[j].x + a[j].y*a[j].y + a[j].z*a[j].z + a[j].w*a[j].w;
        }
        // reduce across the 8 lanes of this row (8-lane groups are xor-closed)
        s  += __shfl_xor(s, 1);  s  += __shfl_xor(s, 2);  s  += __shfl_xor(s, 4);
        s2 += __shfl_xor(s2, 1); s2 += __shfl_xor(s2, 2); s2 += __shfl_xor(s2, 4);
        float mean = s * (1.f / 256.f);
        float var  = s2 * (1.f / 256.f) - mean * mean;
        float rs = rsqrtf(var + 1e-5f);
        #pragma unroll
        for (int j = 0; j < 8; j++) {
            float4 g = ((const float4*)(g0 + cbase))[j];
            float4 bb = ((const float4*)(b0 + cbase))[j];
            short4v y;
            y[0] = f2bf((a[j].x - mean) * rs * g.x + bb.x);
            y[1] = f2bf((a[j].y - mean) * rs * g.y + bb.y);
            y[2] = f2bf((a[j].z - mean) * rs * g.z + bb.z);
            y[3] = f2bf((a[j].w - mean) * rs * g.w + bb.w);
            *(short4v*)(&Xs[lrow][cbase + j * 4]) = y;
        }
    }
    __syncthreads();

    // ---- Phase 2: GEMM from LDS. Wave covers 32 rows x 64 cols. ----
    const int lane = tid & 63, wid = tid >> 6;
    const int m = lane & 15, quad = lane >> 4;
    const int c0 = wid * 64;

    f32x4 acc0[4], acc1[4];                        // rows 0-15 / 16-31
    #pragma unroll
    for (int t = 0; t < 4; t++) {
        acc0[t] = (f32x4){0.f, 0.f, 0.f, 0.f};
        acc1[t] = (f32x4){0.f, 0.f, 0.f, 0.f};
    }

    for (int kk = 0; kk < 256; kk += 32) {
        short8 af0 = *(const short8*)(&Xs[m][kk + quad * 8]);
        short8 af1 = *(const short8*)(&Xs[16 + m][kk + quad * 8]);
        #pragma unroll
        for (int t = 0; t < 4; t++) {
            short8 bf = *(const short8*)(WoT + (c0 + t * 16 + m) * 256 + kk + quad * 8);
            acc0[t] = __builtin_amdgcn_mfma_f32_16x16x32_bf16(af0, bf, acc0[t], 0, 0, 0);
            acc1[t] = __builtin_amdgcn_mfma_f32_16x16x32_bf16(af1, bf, acc1[t], 0, 0, 0);
        }
    }

    // ---- Phase 3: y = x + relu(c + bo); LN1 stats per row-half ----
    float s1[2][4] = {{0.f,0.f,0.f,0.f},{0.f,0.f,0.f,0.f}};
    float s2v[2][4] = {{0.f,0.f,0.f,0.f},{0.f,0.f,0.f,0.f}};
    #pragma unroll
    for (int t = 0; t < 4; t++) {
        int n = c0 + t * 16 + m;
        float bon = bo[n];
        #pragma unroll
        for (int reg = 0; reg < 4; reg++) {
            int r = quad * 4 + reg;
            float xv0 = bf2f(Xs[r][n]);
            float c0v = acc0[t][reg] + bon;
            float yv0 = xv0 + (c0v > 0.f ? c0v : 0.f);
            acc0[t][reg] = yv0;
            s1[0][reg] += yv0;  s2v[0][reg] += yv0 * yv0;
            float xv1 = bf2f(Xs[16 + r][n]);
            float c1v = acc1[t][reg] + bon;
            float yv1 = xv1 + (c1v > 0.f ? c1v : 0.f);
            acc1[t][reg] = yv1;
            s1[1][reg] += yv1;  s2v[1][reg] += yv1 * yv1;
        }
    }
    #pragma unroll
    for (int sub = 0; sub < 2; sub++) {
        #pragma unroll
        for (int reg = 0; reg < 4; reg++) {
            float a = s1[sub][reg], bsum = s2v[sub][reg];
            a += __shfl_xor(a, 1); a += __shfl_xor(a, 2); a += __shfl_xor(a, 4); a += __shfl_xor(a, 8);
            bsum += __shfl_xor(bsum, 1); bsum += __shfl_xor(bsum, 2); bsum += __shfl_xor(bsum, 4); bsum += __shfl_xor(bsum, 8);
            s1[sub][reg] = a; s2v[sub][reg] = bsum;
        }
    }
    if (m == 0) {
        #pragma unroll
        for (int sub = 0; sub < 2; sub++)
            #pragma unroll
            for (int reg = 0; reg < 4; reg++) {
                st[wid][0][sub * 16 + quad * 4 + reg] = s1[sub][reg];
                st[wid][1][sub * 16 + quad * 4 + reg] = s2v[sub][reg];
            }
    }
    __syncthreads();
    #pragma unroll
    for (int sub = 0; sub < 2; sub++) {
        #pragma unroll
        for (int reg = 0; reg < 4; reg++) {
            int r = sub * 16 + quad * 4 + reg;
            float t1 = st[0][0][r] + st[1][0][r] + st[2][0][r] + st[3][0][r];
            float t2 = st[0][1][r] + st[1][1][r] + st[2][1][r] + st[3][1][r];
            float mean = t1 * (1.f / 256.f);
            float var  = t2 * (1.f / 256.f) - mean * mean;
            float rs = rsqrtf(var + 1e-5f);
            int token = r0 + r;
            #pragma unroll
            for (int t = 0; t < 4; t++) {
                int n = c0 + t * 16 + m;
                float yv = (sub == 0) ? acc0[t][reg] : acc1[t][reg];
                out[(size_t)token * 256 + n] = (yv - mean) * rs * g1[n] + b1[n];
            }
        }
    }
}

extern "C" void kernel_launch(void* const* d_in, const int* in_sizes, int n_in,
                              void* d_out, int out_size, void* d_ws, size_t ws_size,
                              hipStream_t stream) {
    const float* Q   = (const float*)d_in[0];
    const float* K   = (const float*)d_in[1];
    const int* lengths = (const int*)d_in[2];
    const float* Wq  = (const float*)d_in[3];
    const float* bq  = (const float*)d_in[4];
    const float* Wk  = (const float*)d_in[5];
    const float* bk  = (const float*)d_in[6];
    const float* Wv  = (const float*)d_in[7];
    const float* bv  = (const float*)d_in[8];
    const float* Wo  = (const float*)d_in[9];
    const float* bo  = (const float*)d_in[10];
    const float* g0  = (const float*)d_in[11];
    const float* b0  = (const float*)d_in[12];
    const float* g1  = (const float*)d_in[13];
    const float* b1  = (const float*)d_in[14];
    float* out = (float*)d_out;

    char* ws = (char*)d_ws;
    short* qb  = (short*)(ws);                         // [8][8][1024][32] bf16, 4 MB
    short* kb  = (short*)(ws + (4u << 20));            // 4 MB (pre-scaled by 1/16)
    short* vT  = (short*)(ws + (8u << 20));            // [8][8][32][1024] bf16, 4 MB
    float* O1  = (float*)(ws + (12u << 20));           // [8192][256] f32, 8 MB
    short* WqT = (short*)(ws + (20u << 20));           // 128 KB each, [n][k] bf16
    short* WkT = (short*)(ws + (20u << 20) + (128u << 10));
    short* WvT = (short*)(ws + (20u << 20) + (256u << 10));
    short* WoT = (short*)(ws + (20u << 20) + (384u << 10));

    wtrans_kernel<<<dim3(16, 4), 256, 0, stream>>>(Wq, Wk, Wv, Wo, WqT, WkT, WvT, WoT);
    proj_kernel<<<dim3(256, 2), 256, 0, stream>>>(Q, K, WqT, WkT, WvT, bq, bk, bv,
                                                  lengths, qb, kb, vT);
    attn_kernel<<<dim3(8, 64), 256, 0, stream>>>(qb, kb, vT, lengths, O1);
    out_kernel<<<dim3(256), 256, 0, stream>>>(O1, WoT, g0, b0, bo, g1, b1, out);
}

// Round 7
// 151.277 us; speedup vs baseline: 1.0657x; 1.0657x over previous
//
#include <hip/hip_runtime.h>
#include <hip/hip_bf16.h>

// Problem: B=8, N=1024, DQ=DK=DV=256, H=8, head_dim=32.
// Pipeline (all bf16 MFMA, fp32 accum):
//   K0 wtrans : W[k][n] f32 -> WT[n][k] bf16 (LDS tile transpose, coalesced both ways)
//   K1 proj   : y=0: q=(Q@Wq+bq)*mask ; y=1: k AND v from one pass over K.
//               A tile staged once per block in LDS bf16; k pre-scaled by 1/sqrt(DV)
//               (kb feeds only QK^T). q,k: [b][h][n][32] ; v: [b][h][32][n] (transposed)
//   K2 attn   : 64 q-rows/block = 4 qh-waves sharing K/V chunks via double-buffered LDS
//               (K,V read ONCE per block from L2: 4x traffic cut vs split-K version);
//               next-chunk loads issued before the barrier (latency hidden under compute);
//               one barrier/chunk; wave-private P tile; direct per-wave epilogue.
//   K3 fused  : LN0(g0,b0) -> x (LDS, bf16); y = x + relu(x@Wo+bo); out = LN1(y)
// NOTE (R6 lesson): these kernels are occupancy/latency-bound, not L2-BW-bound.
// Bigger tiles (128-row attn, 32-row out) cut traffic but dropped active blocks/CU
// to ~1 and regressed +11us. Keep >=2 blocks/CU and >=1024 blocks where possible.

typedef __attribute__((ext_vector_type(8))) short short8;
typedef __attribute__((ext_vector_type(4))) short short4v;
typedef __attribute__((ext_vector_type(4))) float f32x4;

__device__ __forceinline__ short f2bf(float f) {
    union { float f; unsigned u; } x; x.f = f;
    unsigned r = x.u + 0x7fffu + ((x.u >> 16) & 1u);   // RNE
    return (short)(r >> 16);
}
__device__ __forceinline__ float bf2f(short s) {
    union { unsigned u; float f; } x; x.u = ((unsigned)(unsigned short)s) << 16;
    return x.f;
}

// ---------------- K0: transpose + convert weights (coalesced via LDS) ----------------
// grid (16, 4): x = 64x64 tile (4x4 tiling of 256x256), y = which matrix. 256 threads.
__global__ __launch_bounds__(256) void wtrans_kernel(
    const float* __restrict__ Wq, const float* __restrict__ Wk,
    const float* __restrict__ Wv, const float* __restrict__ Wo,
    short* __restrict__ WqT, short* __restrict__ WkT,
    short* __restrict__ WvT, short* __restrict__ WoT)
{
    __shared__ short tile[64][72];                 // +8 pad: breaks pow2 stride
    const float* W; short* T;
    switch (blockIdx.y) {
        case 0:  W = Wq; T = WqT; break;
        case 1:  W = Wk; T = WkT; break;
        case 2:  W = Wv; T = WvT; break;
        default: W = Wo; T = WoT; break;
    }
    const int k0 = (blockIdx.x >> 2) * 64;         // source row tile
    const int n0 = (blockIdx.x & 3) * 64;          // source col tile
    const int c  = threadIdx.x & 63;
    const int r4 = threadIdx.x >> 6;
    #pragma unroll
    for (int i = 0; i < 16; i++) {
        int k = r4 + i * 4;
        tile[k][c] = f2bf(W[(size_t)(k0 + k) * 256 + n0 + c]);   // coalesced read
    }
    __syncthreads();
    #pragma unroll
    for (int i = 0; i < 16; i++) {
        int n = r4 + i * 4;
        T[(size_t)(n0 + n) * 256 + k0 + c] = tile[c][n];         // coalesced write
    }
}

// ---------------- K1: projections ----------------
// grid (256, 2) blocks of 256. Block: 32 token rows x 256 cols.
// y=0: q only. y=1: k AND v (one A pass, two MFMA chains). A tile staged in LDS.
__global__ __launch_bounds__(256) void proj_kernel(
    const float* __restrict__ Q, const float* __restrict__ Kin,
    const short* __restrict__ WqT, const short* __restrict__ WkT, const short* __restrict__ WvT,
    const float* __restrict__ bq, const float* __restrict__ bk, const float* __restrict__ bv,
    const int* __restrict__ lengths,
    short* __restrict__ qb, short* __restrict__ kb, short* __restrict__ vT)
{
    __shared__ short Xt[32][264];                 // A tile bf16; stride 528B -> 2-way (free)
    const int which = blockIdx.y;                 // 0=q, 1=k+v
    const float* A   = (which == 0) ? Q   : Kin;
    const short* WTa = (which == 0) ? WqT : WkT;

    const int tid = threadIdx.x;
    const int b = blockIdx.x >> 5;                // batch (32 rows/block, 32 blocks/batch)
    const int len = lengths[b];
    const int r0b = blockIdx.x * 32;              // block's token row base (global)
    const int ntok0b = r0b & 1023;                // within-batch row base of block

    // ---- stage A tile: 32 rows x 256 cols, f32 -> bf16, coalesced, converted once ----
    if (ntok0b < len) {
        #pragma unroll
        for (int it = 0; it < 8; it++) {
            int e = tid + it * 256;               // 2048 float4 loads total
            int row = e >> 6, c4 = (e & 63) * 4;
            float4 f = *(const float4*)(A + (size_t)(r0b + row) * 256 + c4);
            short4v s4;
            s4[0] = f2bf(f.x); s4[1] = f2bf(f.y); s4[2] = f2bf(f.z); s4[3] = f2bf(f.w);
            *(short4v*)(&Xt[row][c4]) = s4;
        }
    }
    __syncthreads();

    const int lane = tid & 63, wid = tid >> 6;
    const int m = lane & 15, quad = lane >> 4;
    const int rh = wid >> 1, ch = wid & 1;
    const int c0 = ch * 128;                      // wave's column base
    const int ntok0 = ntok0b + rh * 16;           // wave's within-batch row base

    f32x4 accA[8], accB[8];
    #pragma unroll
    for (int t = 0; t < 8; t++) {
        accA[t] = (f32x4){0.f, 0.f, 0.f, 0.f};
        accB[t] = (f32x4){0.f, 0.f, 0.f, 0.f};
    }

    if (ntok0 < len) {                            // fully-masked wave tiles: skip GEMM
        for (int kk = 0; kk < 256; kk += 32) {
            short8 af = *(const short8*)(&Xt[rh * 16 + m][kk + quad * 8]);
            #pragma unroll
            for (int t = 0; t < 8; t++) {
                short8 bfa = *(const short8*)(WTa + (c0 + t * 16 + m) * 256 + kk + quad * 8);
                accA[t] = __builtin_amdgcn_mfma_f32_16x16x32_bf16(af, bfa, accA[t], 0, 0, 0);
            }
            if (which == 1) {
                #pragma unroll
                for (int t = 0; t < 8; t++) {
                    short8 bfb = *(const short8*)(WvT + (c0 + t * 16 + m) * 256 + kk + quad * 8);
                    accB[t] = __builtin_amdgcn_mfma_f32_16x16x32_bf16(af, bfb, accB[t], 0, 0, 0);
                }
            }
        }
    }

    const float KSCALE = 0.0625f;                  // 1/sqrt(256), folded into kb
    #pragma unroll
    for (int t = 0; t < 8; t++) {
        int n = c0 + t * 16 + m;                   // output column
        int h = n >> 5, i = n & 31;
        int bh = b * 8 + h;
        if (which == 0) {
            float bias = bq[n];
            #pragma unroll
            for (int reg = 0; reg < 4; reg++) {
                int ntok = ntok0 + quad * 4 + reg; // C layout: row = quad*4+reg
                float val = (ntok < len) ? (accA[t][reg] + bias) : 0.f;
                qb[((size_t)bh * 1024 + ntok) * 32 + i] = f2bf(val);
            }
        } else {
            float bk_ = bk[n];
            float bv_ = bv[n];
            #pragma unroll
            for (int reg = 0; reg < 4; reg++) {
                int ntok = ntok0 + quad * 4 + reg;
                bool ok = ntok < len;
                float vk = ok ? (accA[t][reg] + bk_) * KSCALE : 0.f;
                float vv = ok ? (accB[t][reg] + bv_) : 0.f;
                kb[((size_t)bh * 1024 + ntok) * 32 + i] = f2bf(vk);
                vT[(size_t)(bh * 32 + i) * 1024 + ntok] = f2bf(vv);
            }
        }
    }
}

// ---------------- K2: attention ----------------
// grid (16, 64): x = 64-row q-tile, y = b*8+h. Block 256 = 4 waves; wave wid owns
// q-rows [bx*64 + wid*16, +16). All waves share each 64-key K/V chunk, staged in
// double-buffered LDS (read once per block from L2). One barrier per chunk;
// next-chunk global loads issued before the barrier so L2/HBM latency hides
// under the current chunk's compute. P tile stays wave-private.
__global__ __launch_bounds__(256) void attn_kernel(
    const short* __restrict__ qb, const short* __restrict__ kb, const short* __restrict__ vT,
    const int* __restrict__ lengths, float* __restrict__ O1)
{
    __shared__ short Kb[2][64][36];                // 9216 B  (row stride 18 dw: <=2-way)
    __shared__ short Vb[2][32][76];                // 9728 B  (row stride 38 dw: ~2-way)
    __shared__ short P[4][16][72];                 // 9216 B  (wave-private)
    const int tid = threadIdx.x;
    const int lane = tid & 63, wid = tid >> 6;
    const int m = lane & 15, quad = lane >> 4;
    const int bh = blockIdx.y;
    const int b = bh >> 3, h = bh & 7;
    const int len = lengths[b];
    const int qr0 = blockIdx.x * 64 + wid * 16;
    const bool active = qr0 < len;

    const short* qbase = qb + (size_t)bh * 1024 * 32;
    const short* kbase = kb + (size_t)bh * 1024 * 32;
    const short* vbase = vT + (size_t)bh * 32 * 1024;

    // A-frag of q: rows qr0..qr0+15, k-dim 32 == one MFMA K step. Load once.
    const short8 qf = *(const short8*)(qbase + (qr0 + m) * 32 + quad * 8);

    f32x4 o0 = (f32x4){0.f, 0.f, 0.f, 0.f};       // vdims 0..15
    f32x4 o1 = (f32x4){0.f, 0.f, 0.f, 0.f};       // vdims 16..31
    float l[4] = {0.f, 0.f, 0.f, 0.f};            // rowsum partials (row = quad*4+reg)

    // block-uniform chunk count (block skips entirely if its 64 rows are all masked)
    const int nch = (blockIdx.x * 64 < len) ? ((len + 63) >> 6) : 0;

    short8 kr, vr;
    if (nch > 0) {                                 // prologue loads for chunk 0
        kr = *(const short8*)(kbase + tid * 8);
        vr = *(const short8*)(vbase + (size_t)(tid >> 3) * 1024 + (tid & 7) * 8);
    }

    for (int ci = 0; ci < nch; ci++) {
        const int buf = ci & 1;
        // stage current chunk (regs -> LDS); K: row tid>>2, V: row tid>>3
        *(short8*)(&Kb[buf][tid >> 2][(tid & 3) * 8]) = kr;
        *(short8*)(&Vb[buf][tid >> 3][(tid & 7) * 8]) = vr;
        if (ci + 1 < nch) {                        // issue next chunk's loads now
            int k1 = (ci + 1) * 64;
            kr = *(const short8*)(kbase + k1 * 32 + tid * 8);
            vr = *(const short8*)(vbase + (size_t)(tid >> 3) * 1024 + k1 + (tid & 7) * 8);
        }
        __syncthreads();                           // staged chunk visible to all waves

        if (active) {
            const int key0 = ci * 64;
            #pragma unroll
            for (int t = 0; t < 4; t++) {
                short8 kf = *(const short8*)(&Kb[buf][t * 16 + m][quad * 8]);
                f32x4 s = __builtin_amdgcn_mfma_f32_16x16x32_bf16(qf, kf,
                            (f32x4){0.f, 0.f, 0.f, 0.f}, 0, 0, 0);
                int col = key0 + t * 16 + m;       // key index (C layout col)
                bool cm = col < len;
                #pragma unroll
                for (int reg = 0; reg < 4; reg++) {
                    float e = cm ? __expf(s[reg]) : 0.f;   // scale pre-folded into kb
                    l[reg] += e;
                    P[wid][quad * 4 + reg][t * 16 + m] = f2bf(e);
                }
            }
            // wave-private P ordering only (no block barrier)
            asm volatile("s_waitcnt lgkmcnt(0)" ::: "memory");
            #pragma unroll
            for (int c = 0; c < 2; c++) {
                short8 pf  = *(const short8*)(&P[wid][m][c * 32 + quad * 8]);
                short8 vf0 = *(const short8*)(&Vb[buf][m][c * 32 + quad * 8]);
                short8 vf1 = *(const short8*)(&Vb[buf][16 + m][c * 32 + quad * 8]);
                o0 = __builtin_amdgcn_mfma_f32_16x16x32_bf16(pf, vf0, o0, 0, 0, 0);
                o1 = __builtin_amdgcn_mfma_f32_16x16x32_bf16(pf, vf1, o1, 0, 0, 0);
            }
        }
    }

    // reduce rowsums across the 16 lanes of each quad group
    #pragma unroll
    for (int reg = 0; reg < 4; reg++) {
        float s = l[reg];
        s += __shfl_xor(s, 1); s += __shfl_xor(s, 2);
        s += __shfl_xor(s, 4); s += __shfl_xor(s, 8);
        l[reg] = s;
    }

    // direct per-wave epilogue (each wave owns its 16 q-rows; no split-K combine)
    const int hbase = h * 32;
    #pragma unroll
    for (int reg = 0; reg < 4; reg++) {
        int qrow = qr0 + quad * 4 + reg;           // within-batch row (C layout)
        float f = (qrow < len) ? 1.f / (l[reg] + 1e-15f) : 0.f;
        size_t obase = ((size_t)(b * 1024 + qrow)) * 256 + hbase;
        float q0 = bf2f(qbase[qrow * 32 + m]);
        float q1 = bf2f(qbase[qrow * 32 + 16 + m]);
        O1[obase + m]      = q0 + o0[reg] * f;
        O1[obase + 16 + m] = q1 + o1[reg] * f;
    }
}

// ---------------- K3: fused LN0 + output projection + relu residual + LN1 ----------------
// grid 512 blocks of 256 (4 waves). Block: 16 token rows x full 256 cols.
// Phase 1: LN0 from O1 -> normalized bf16 x staged in LDS (no global Xb).
// Phase 2: GEMM x@Wo from LDS A-fragments; wave = 16 rows x 64 cols (c0 = wid*64).
// Phase 3: y = x + relu(c+bo); LN1 row stats across 4 col-quarter waves via LDS.
__global__ __launch_bounds__(256) void out_kernel(
    const float* __restrict__ O1, const short* __restrict__ WoT,
    const float* __restrict__ g0, const float* __restrict__ b0,
    const float* __restrict__ bo, const float* __restrict__ g1, const float* __restrict__ b1,
    float* __restrict__ out)
{
    __shared__ short Xs[16][264];                  // normalized x, bf16, padded stride
    __shared__ float st[4][2][16];                 // [wave][{s1,s2}][row]
    const int tid = threadIdx.x;
    const int r0 = blockIdx.x * 16;

    // ---- Phase 1: LN0. 16 threads per row, 16 cols per thread. ----
    {
        const int lrow  = tid >> 4;                // 0..15
        const int cbase = (tid & 15) * 16;
        const float* rowp = O1 + (size_t)(r0 + lrow) * 256 + cbase;
        float4 a0 = ((const float4*)rowp)[0];
        float4 a1 = ((const float4*)rowp)[1];
        float4 a2 = ((const float4*)rowp)[2];
        float4 a3 = ((const float4*)rowp)[3];
        float s  = a0.x + a0.y + a0.z + a0.w + a1.x + a1.y + a1.z + a1.w
                 + a2.x + a2.y + a2.z + a2.w + a3.x + a3.y + a3.z + a3.w;
        float s2 = a0.x*a0.x + a0.y*a0.y + a0.z*a0.z + a0.w*a0.w
                 + a1.x*a1.x + a1.y*a1.y + a1.z*a1.z + a1.w*a1.w
                 + a2.x*a2.x + a2.y*a2.y + a2.z*a2.z + a2.w*a2.w
                 + a3.x*a3.x + a3.y*a3.y + a3.z*a3.z + a3.w*a3.w;
        // reduce across the 16 lanes of this row (lanes are 16-aligned groups)
        s  += __shfl_xor(s, 1);  s  += __shfl_xor(s, 2);
        s  += __shfl_xor(s, 4);  s  += __shfl_xor(s, 8);
        s2 += __shfl_xor(s2, 1); s2 += __shfl_xor(s2, 2);
        s2 += __shfl_xor(s2, 4); s2 += __shfl_xor(s2, 8);
        float mean = s * (1.f / 256.f);
        float var  = s2 * (1.f / 256.f) - mean * mean;
        float rs = rsqrtf(var + 1e-5f);
        float4 g0a = ((const float4*)(g0 + cbase))[0];
        float4 g0b = ((const float4*)(g0 + cbase))[1];
        float4 g0c = ((const float4*)(g0 + cbase))[2];
        float4 g0d = ((const float4*)(g0 + cbase))[3];
        float4 b0a = ((const float4*)(b0 + cbase))[0];
        float4 b0b = ((const float4*)(b0 + cbase))[1];
        float4 b0c = ((const float4*)(b0 + cbase))[2];
        float4 b0d = ((const float4*)(b0 + cbase))[3];
        short8 y0, y1;
        y0[0] = f2bf((a0.x - mean) * rs * g0a.x + b0a.x);
        y0[1] = f2bf((a0.y - mean) * rs * g0a.y + b0a.y);
        y0[2] = f2bf((a0.z - mean) * rs * g0a.z + b0a.z);
        y0[3] = f2bf((a0.w - mean) * rs * g0a.w + b0a.w);
        y0[4] = f2bf((a1.x - mean) * rs * g0b.x + b0b.x);
        y0[5] = f2bf((a1.y - mean) * rs * g0b.y + b0b.y);
        y0[6] = f2bf((a1.z - mean) * rs * g0b.z + b0b.z);
        y0[7] = f2bf((a1.w - mean) * rs * g0b.w + b0b.w);
        y1[0] = f2bf((a2.x - mean) * rs * g0c.x + b0c.x);
        y1[1] = f2bf((a2.y - mean) * rs * g0c.y + b0c.y);
        y1[2] = f2bf((a2.z - mean) * rs * g0c.z + b0c.z);
        y1[3] = f2bf((a2.w - mean) * rs * g0c.w + b0c.w);
        y1[4] = f2bf((a3.x - mean) * rs * g0d.x + b0d.x);
        y1[5] = f2bf((a3.y - mean) * rs * g0d.y + b0d.y);
        y1[6] = f2bf((a3.z - mean) * rs * g0d.z + b0d.z);
        y1[7] = f2bf((a3.w - mean) * rs * g0d.w + b0d.w);
        *(short8*)(&Xs[lrow][cbase])     = y0;
        *(short8*)(&Xs[lrow][cbase + 8]) = y1;
    }
    __syncthreads();

    // ---- Phase 2: GEMM from LDS. Wave covers 16 rows x 64 cols. ----
    const int lane = tid & 63, wid = tid >> 6;
    const int m = lane & 15, quad = lane >> 4;
    const int c0 = wid * 64;

    f32x4 acc[4];
    #pragma unroll
    for (int t = 0; t < 4; t++) acc[t] = (f32x4){0.f, 0.f, 0.f, 0.f};

    for (int kk = 0; kk < 256; kk += 32) {
        short8 af = *(const short8*)(&Xs[m][kk + quad * 8]);
        #pragma unroll
        for (int t = 0; t < 4; t++) {
            short8 bf = *(const short8*)(WoT + (c0 + t * 16 + m) * 256 + kk + quad * 8);
            acc[t] = __builtin_amdgcn_mfma_f32_16x16x32_bf16(af, bf, acc[t], 0, 0, 0);
        }
    }

    // ---- Phase 3: y = x + relu(c + bo); LN1 stats over this col-quarter ----
    float s1[4] = {0.f, 0.f, 0.f, 0.f};
    float s2v[4] = {0.f, 0.f, 0.f, 0.f};
    #pragma unroll
    for (int t = 0; t < 4; t++) {
        int n = c0 + t * 16 + m;
        float bon = bo[n];
        #pragma unroll
        for (int reg = 0; reg < 4; reg++) {
            int r = quad * 4 + reg;
            float xv = bf2f(Xs[r][n]);
            float c = acc[t][reg] + bon;
            float yv = xv + (c > 0.f ? c : 0.f);
            acc[t][reg] = yv;                       // reuse acc as y storage
            s1[reg] += yv;
            s2v[reg] += yv * yv;
        }
    }
    #pragma unroll
    for (int reg = 0; reg < 4; reg++) {
        float a = s1[reg], bsum = s2v[reg];
        a += __shfl_xor(a, 1); a += __shfl_xor(a, 2); a += __shfl_xor(a, 4); a += __shfl_xor(a, 8);
        bsum += __shfl_xor(bsum, 1); bsum += __shfl_xor(bsum, 2); bsum += __shfl_xor(bsum, 4); bsum += __shfl_xor(bsum, 8);
        s1[reg] = a; s2v[reg] = bsum;
    }
    if (m == 0) {
        #pragma unroll
        for (int reg = 0; reg < 4; reg++) {
            st[wid][0][quad * 4 + reg] = s1[reg];
            st[wid][1][quad * 4 + reg] = s2v[reg];
        }
    }
    __syncthreads();
    #pragma unroll
    for (int reg = 0; reg < 4; reg++) {
        int r = quad * 4 + reg;
        float t1 = st[0][0][r] + st[1][0][r] + st[2][0][r] + st[3][0][r];
        float t2 = st[0][1][r] + st[1][1][r] + st[2][1][r] + st[3][1][r];
        float mean = t1 * (1.f / 256.f);
        float var  = t2 * (1.f / 256.f) - mean * mean;
        float rs = rsqrtf(var + 1e-5f);
        int token = r0 + r;
        #pragma unroll
        for (int t = 0; t < 4; t++) {
            int n = c0 + t * 16 + m;
            out[(size_t)token * 256 + n] = (acc[t][reg] - mean) * rs * g1[n] + b1[n];
        }
    }
}

extern "C" void kernel_launch(void* const* d_in, const int* in_sizes, int n_in,
                              void* d_out, int out_size, void* d_ws, size_t ws_size,
                              hipStream_t stream) {
    const float* Q   = (const float*)d_in[0];
    const float* K   = (const float*)d_in[1];
    const int* lengths = (const int*)d_in[2];
    const float* Wq  = (const float*)d_in[3];
    const float* bq  = (const float*)d_in[4];
    const float* Wk  = (const float*)d_in[5];
    const float* bk  = (const float*)d_in[6];
    const float* Wv  = (const float*)d_in[7];
    const float* bv  = (const float*)d_in[8];
    const float* Wo  = (const float*)d_in[9];
    const float* bo  = (const float*)d_in[10];
    const float* g0  = (const float*)d_in[11];
    const float* b0  = (const float*)d_in[12];
    const float* g1  = (const float*)d_in[13];
    const float* b1  = (const float*)d_in[14];
    float* out = (float*)d_out;

    char* ws = (char*)d_ws;
    short* qb  = (short*)(ws);                         // [8][8][1024][32] bf16, 4 MB
    short* kb  = (short*)(ws + (4u << 20));            // 4 MB (pre-scaled by 1/16)
    short* vT  = (short*)(ws + (8u << 20));            // [8][8][32][1024] bf16, 4 MB
    float* O1  = (float*)(ws + (12u << 20));           // [8192][256] f32, 8 MB
    short* WqT = (short*)(ws + (20u << 20));           // 128 KB each, [n][k] bf16
    short* WkT = (short*)(ws + (20u << 20) + (128u << 10));
    short* WvT = (short*)(ws + (20u << 20) + (256u << 10));
    short* WoT = (short*)(ws + (20u << 20) + (384u << 10));

    wtrans_kernel<<<dim3(16, 4), 256, 0, stream>>>(Wq, Wk, Wv, Wo, WqT, WkT, WvT, WoT);
    proj_kernel<<<dim3(256, 2), 256, 0, stream>>>(Q, K, WqT, WkT, WvT, bq, bk, bv,
                                                  lengths, qb, kb, vT);
    attn_kernel<<<dim3(16, 64), 256, 0, stream>>>(qb, kb, vT, lengths, O1);
    out_kernel<<<dim3(512), 256, 0, stream>>>(O1, WoT, g0, b0, bo, g1, b1, out);
}

// Round 8
// 150.508 us; speedup vs baseline: 1.0712x; 1.0051x over previous
//
#include <hip/hip_runtime.h>
#include <hip/hip_bf16.h>

// Problem: B=8, N=1024, DQ=DK=DV=256, H=8, head_dim=32.
// Pipeline (all bf16 MFMA, fp32 accum):
//   K0 wtrans : W[k][n] f32 -> WT[n][k] bf16 (LDS tile transpose, coalesced both ways)
//   K1 proj   : y=0: q=(Q@Wq+bq)*mask ; y=1: k AND v from one pass over K.
//               A tile staged once per block in LDS bf16; k pre-scaled by 1/sqrt(DV)
//               (kb feeds only QK^T). q,k: [b][h][n][32] ; v: [b][h][32][n] (transposed)
//   K2 attn   : 64 q-rows/block = 4 qh-waves sharing K/V chunks via double-buffered LDS
//               (K,V read ONCE per block from L2); next-chunk loads issued before the
//               barrier; one barrier/chunk; wave-private P tile; direct per-wave epilogue.
//   K3 fused  : LN0(g0,b0) -> x (LDS, bf16); y = x + relu(x@Wo+bo); out = LN1(y)
// NOTE (R6 lesson): these kernels are occupancy/latency-bound, not L2-BW-bound.
// Bigger tiles (128-row attn, 32-row out) cut traffic but dropped active blocks/CU
// to ~1 and regressed +11us. Keep >=2 blocks/CU and >=1024 blocks where possible.
// R7: f2bf = single v_cvt_pk_bf16_f32 (RNE, same rounding as the old bit-trick;
// no HIP builtin on gfx950 -> inline asm). 4x fewer VALU ops per conversion.

typedef __attribute__((ext_vector_type(8))) short short8;
typedef __attribute__((ext_vector_type(4))) short short4v;
typedef __attribute__((ext_vector_type(4))) float f32x4;

__device__ __forceinline__ short f2bf(float f) {
    unsigned r;
    asm("v_cvt_pk_bf16_f32 %0, %1, 0" : "=v"(r) : "v"(f));   // RNE, low 16 bits
    return (short)r;
}
__device__ __forceinline__ float bf2f(short s) {
    union { unsigned u; float f; } x; x.u = ((unsigned)(unsigned short)s) << 16;
    return x.f;
}

// ---------------- K0: transpose + convert weights (coalesced via LDS) ----------------
// grid (16, 4): x = 64x64 tile (4x4 tiling of 256x256), y = which matrix. 256 threads.
__global__ __launch_bounds__(256) void wtrans_kernel(
    const float* __restrict__ Wq, const float* __restrict__ Wk,
    const float* __restrict__ Wv, const float* __restrict__ Wo,
    short* __restrict__ WqT, short* __restrict__ WkT,
    short* __restrict__ WvT, short* __restrict__ WoT)
{
    __shared__ short tile[64][72];                 // +8 pad: breaks pow2 stride
    const float* W; short* T;
    switch (blockIdx.y) {
        case 0:  W = Wq; T = WqT; break;
        case 1:  W = Wk; T = WkT; break;
        case 2:  W = Wv; T = WvT; break;
        default: W = Wo; T = WoT; break;
    }
    const int k0 = (blockIdx.x >> 2) * 64;         // source row tile
    const int n0 = (blockIdx.x & 3) * 64;          // source col tile
    const int c  = threadIdx.x & 63;
    const int r4 = threadIdx.x >> 6;
    #pragma unroll
    for (int i = 0; i < 16; i++) {
        int k = r4 + i * 4;
        tile[k][c] = f2bf(W[(size_t)(k0 + k) * 256 + n0 + c]);   // coalesced read
    }
    __syncthreads();
    #pragma unroll
    for (int i = 0; i < 16; i++) {
        int n = r4 + i * 4;
        T[(size_t)(n0 + n) * 256 + k0 + c] = tile[c][n];         // coalesced write
    }
}

// ---------------- K1: projections ----------------
// grid (256, 2) blocks of 256. Block: 32 token rows x 256 cols.
// y=0: q only. y=1: k AND v (one A pass, two MFMA chains). A tile staged in LDS.
__global__ __launch_bounds__(256) void proj_kernel(
    const float* __restrict__ Q, const float* __restrict__ Kin,
    const short* __restrict__ WqT, const short* __restrict__ WkT, const short* __restrict__ WvT,
    const float* __restrict__ bq, const float* __restrict__ bk, const float* __restrict__ bv,
    const int* __restrict__ lengths,
    short* __restrict__ qb, short* __restrict__ kb, short* __restrict__ vT)
{
    __shared__ short Xt[32][264];                 // A tile bf16; stride 528B -> 2-way (free)
    const int which = blockIdx.y;                 // 0=q, 1=k+v
    const float* A   = (which == 0) ? Q   : Kin;
    const short* WTa = (which == 0) ? WqT : WkT;

    const int tid = threadIdx.x;
    const int b = blockIdx.x >> 5;                // batch (32 rows/block, 32 blocks/batch)
    const int len = lengths[b];
    const int r0b = blockIdx.x * 32;              // block's token row base (global)
    const int ntok0b = r0b & 1023;                // within-batch row base of block

    // ---- stage A tile: 32 rows x 256 cols, f32 -> bf16, coalesced, converted once ----
    if (ntok0b < len) {
        #pragma unroll
        for (int it = 0; it < 8; it++) {
            int e = tid + it * 256;               // 2048 float4 loads total
            int row = e >> 6, c4 = (e & 63) * 4;
            float4 f = *(const float4*)(A + (size_t)(r0b + row) * 256 + c4);
            short4v s4;
            s4[0] = f2bf(f.x); s4[1] = f2bf(f.y); s4[2] = f2bf(f.z); s4[3] = f2bf(f.w);
            *(short4v*)(&Xt[row][c4]) = s4;
        }
    }
    __syncthreads();

    const int lane = tid & 63, wid = tid >> 6;
    const int m = lane & 15, quad = lane >> 4;
    const int rh = wid >> 1, ch = wid & 1;
    const int c0 = ch * 128;                      // wave's column base
    const int ntok0 = ntok0b + rh * 16;           // wave's within-batch row base

    f32x4 accA[8], accB[8];
    #pragma unroll
    for (int t = 0; t < 8; t++) {
        accA[t] = (f32x4){0.f, 0.f, 0.f, 0.f};
        accB[t] = (f32x4){0.f, 0.f, 0.f, 0.f};
    }

    if (ntok0 < len) {                            // fully-masked wave tiles: skip GEMM
        for (int kk = 0; kk < 256; kk += 32) {
            short8 af = *(const short8*)(&Xt[rh * 16 + m][kk + quad * 8]);
            #pragma unroll
            for (int t = 0; t < 8; t++) {
                short8 bfa = *(const short8*)(WTa + (c0 + t * 16 + m) * 256 + kk + quad * 8);
                accA[t] = __builtin_amdgcn_mfma_f32_16x16x32_bf16(af, bfa, accA[t], 0, 0, 0);
            }
            if (which == 1) {
                #pragma unroll
                for (int t = 0; t < 8; t++) {
                    short8 bfb = *(const short8*)(WvT + (c0 + t * 16 + m) * 256 + kk + quad * 8);
                    accB[t] = __builtin_amdgcn_mfma_f32_16x16x32_bf16(af, bfb, accB[t], 0, 0, 0);
                }
            }
        }
    }

    const float KSCALE = 0.0625f;                  // 1/sqrt(256), folded into kb
    #pragma unroll
    for (int t = 0; t < 8; t++) {
        int n = c0 + t * 16 + m;                   // output column
        int h = n >> 5, i = n & 31;
        int bh = b * 8 + h;
        if (which == 0) {
            float bias = bq[n];
            #pragma unroll
            for (int reg = 0; reg < 4; reg++) {
                int ntok = ntok0 + quad * 4 + reg; // C layout: row = quad*4+reg
                float val = (ntok < len) ? (accA[t][reg] + bias) : 0.f;
                qb[((size_t)bh * 1024 + ntok) * 32 + i] = f2bf(val);
            }
        } else {
            float bk_ = bk[n];
            float bv_ = bv[n];
            #pragma unroll
            for (int reg = 0; reg < 4; reg++) {
                int ntok = ntok0 + quad * 4 + reg;
                bool ok = ntok < len;
                float vk = ok ? (accA[t][reg] + bk_) * KSCALE : 0.f;
                float vv = ok ? (accB[t][reg] + bv_) : 0.f;
                kb[((size_t)bh * 1024 + ntok) * 32 + i] = f2bf(vk);
                vT[(size_t)(bh * 32 + i) * 1024 + ntok] = f2bf(vv);
            }
        }
    }
}

// ---------------- K2: attention ----------------
// grid (16, 64): x = 64-row q-tile, y = b*8+h. Block 256 = 4 waves; wave wid owns
// q-rows [bx*64 + wid*16, +16). All waves share each 64-key K/V chunk, staged in
// double-buffered LDS (read once per block from L2). One barrier per chunk;
// next-chunk global loads issued before the barrier so L2/HBM latency hides
// under the current chunk's compute. P tile stays wave-private.
__global__ __launch_bounds__(256) void attn_kernel(
    const short* __restrict__ qb, const short* __restrict__ kb, const short* __restrict__ vT,
    const int* __restrict__ lengths, float* __restrict__ O1)
{
    __shared__ short Kb[2][64][36];                // 9216 B  (row stride 18 dw: <=2-way)
    __shared__ short Vb[2][32][76];                // 9728 B  (row stride 38 dw: ~2-way)
    __shared__ short P[4][16][72];                 // 9216 B  (wave-private)
    const int tid = threadIdx.x;
    const int lane = tid & 63, wid = tid >> 6;
    const int m = lane & 15, quad = lane >> 4;
    const int bh = blockIdx.y;
    const int b = bh >> 3, h = bh & 7;
    const int len = lengths[b];
    const int qr0 = blockIdx.x * 64 + wid * 16;
    const bool active = qr0 < len;

    const short* qbase = qb + (size_t)bh * 1024 * 32;
    const short* kbase = kb + (size_t)bh * 1024 * 32;
    const short* vbase = vT + (size_t)bh * 32 * 1024;

    // A-frag of q: rows qr0..qr0+15, k-dim 32 == one MFMA K step. Load once.
    const short8 qf = *(const short8*)(qbase + (qr0 + m) * 32 + quad * 8);

    f32x4 o0 = (f32x4){0.f, 0.f, 0.f, 0.f};       // vdims 0..15
    f32x4 o1 = (f32x4){0.f, 0.f, 0.f, 0.f};       // vdims 16..31
    float l[4] = {0.f, 0.f, 0.f, 0.f};            // rowsum partials (row = quad*4+reg)

    // block-uniform chunk count (block skips entirely if its 64 rows are all masked)
    const int nch = (blockIdx.x * 64 < len) ? ((len + 63) >> 6) : 0;

    short8 kr, vr;
    if (nch > 0) {                                 // prologue loads for chunk 0
        kr = *(const short8*)(kbase + tid * 8);
        vr = *(const short8*)(vbase + (size_t)(tid >> 3) * 1024 + (tid & 7) * 8);
    }

    for (int ci = 0; ci < nch; ci++) {
        const int buf = ci & 1;
        // stage current chunk (regs -> LDS); K: row tid>>2, V: row tid>>3
        *(short8*)(&Kb[buf][tid >> 2][(tid & 3) * 8]) = kr;
        *(short8*)(&Vb[buf][tid >> 3][(tid & 7) * 8]) = vr;
        if (ci + 1 < nch) {                        // issue next chunk's loads now
            int k1 = (ci + 1) * 64;
            kr = *(const short8*)(kbase + k1 * 32 + tid * 8);
            vr = *(const short8*)(vbase + (size_t)(tid >> 3) * 1024 + k1 + (tid & 7) * 8);
        }
        __syncthreads();                           // staged chunk visible to all waves

        if (active) {
            const int key0 = ci * 64;
            #pragma unroll
            for (int t = 0; t < 4; t++) {
                short8 kf = *(const short8*)(&Kb[buf][t * 16 + m][quad * 8]);
                f32x4 s = __builtin_amdgcn_mfma_f32_16x16x32_bf16(qf, kf,
                            (f32x4){0.f, 0.f, 0.f, 0.f}, 0, 0, 0);
                int col = key0 + t * 16 + m;       // key index (C layout col)
                bool cm = col < len;
                #pragma unroll
                for (int reg = 0; reg < 4; reg++) {
                    float e = cm ? __expf(s[reg]) : 0.f;   // scale pre-folded into kb
                    l[reg] += e;
                    P[wid][quad * 4 + reg][t * 16 + m] = f2bf(e);
                }
            }
            // wave-private P ordering only (no block barrier)
            asm volatile("s_waitcnt lgkmcnt(0)" ::: "memory");
            #pragma unroll
            for (int c = 0; c < 2; c++) {
                short8 pf  = *(const short8*)(&P[wid][m][c * 32 + quad * 8]);
                short8 vf0 = *(const short8*)(&Vb[buf][m][c * 32 + quad * 8]);
                short8 vf1 = *(const short8*)(&Vb[buf][16 + m][c * 32 + quad * 8]);
                o0 = __builtin_amdgcn_mfma_f32_16x16x32_bf16(pf, vf0, o0, 0, 0, 0);
                o1 = __builtin_amdgcn_mfma_f32_16x16x32_bf16(pf, vf1, o1, 0, 0, 0);
            }
        }
    }

    // reduce rowsums across the 16 lanes of each quad group
    #pragma unroll
    for (int reg = 0; reg < 4; reg++) {
        float s = l[reg];
        s += __shfl_xor(s, 1); s += __shfl_xor(s, 2);
        s += __shfl_xor(s, 4); s += __shfl_xor(s, 8);
        l[reg] = s;
    }

    // direct per-wave epilogue (each wave owns its 16 q-rows; no split-K combine)
    const int hbase = h * 32;
    #pragma unroll
    for (int reg = 0; reg < 4; reg++) {
        int qrow = qr0 + quad * 4 + reg;           // within-batch row (C layout)
        float f = (qrow < len) ? 1.f / (l[reg] + 1e-15f) : 0.f;
        size_t obase = ((size_t)(b * 1024 + qrow)) * 256 + hbase;
        float q0 = bf2f(qbase[qrow * 32 + m]);
        float q1 = bf2f(qbase[qrow * 32 + 16 + m]);
        O1[obase + m]      = q0 + o0[reg] * f;
        O1[obase + 16 + m] = q1 + o1[reg] * f;
    }
}

// ---------------- K3: fused LN0 + output projection + relu residual + LN1 ----------------
// grid 512 blocks of 256 (4 waves). Block: 16 token rows x full 256 cols.
// Phase 1: LN0 from O1 -> normalized bf16 x staged in LDS (no global Xb).
// Phase 2: GEMM x@Wo from LDS A-fragments; wave = 16 rows x 64 cols (c0 = wid*64).
// Phase 3: y = x + relu(c+bo); LN1 row stats across 4 col-quarter waves via LDS.
__global__ __launch_bounds__(256) void out_kernel(
    const float* __restrict__ O1, const short* __restrict__ WoT,
    const float* __restrict__ g0, const float* __restrict__ b0,
    const float* __restrict__ bo, const float* __restrict__ g1, const float* __restrict__ b1,
    float* __restrict__ out)
{
    __shared__ short Xs[16][264];                  // normalized x, bf16, padded stride
    __shared__ float st[4][2][16];                 // [wave][{s1,s2}][row]
    const int tid = threadIdx.x;
    const int r0 = blockIdx.x * 16;

    // ---- Phase 1: LN0. 16 threads per row, 16 cols per thread. ----
    {
        const int lrow  = tid >> 4;                // 0..15
        const int cbase = (tid & 15) * 16;
        const float* rowp = O1 + (size_t)(r0 + lrow) * 256 + cbase;
        float4 a0 = ((const float4*)rowp)[0];
        float4 a1 = ((const float4*)rowp)[1];
        float4 a2 = ((const float4*)rowp)[2];
        float4 a3 = ((const float4*)rowp)[3];
        float s  = a0.x + a0.y + a0.z + a0.w + a1.x + a1.y + a1.z + a1.w
                 + a2.x + a2.y + a2.z + a2.w + a3.x + a3.y + a3.z + a3.w;
        float s2 = a0.x*a0.x + a0.y*a0.y + a0.z*a0.z + a0.w*a0.w
                 + a1.x*a1.x + a1.y*a1.y + a1.z*a1.z + a1.w*a1.w
                 + a2.x*a2.x + a2.y*a2.y + a2.z*a2.z + a2.w*a2.w
                 + a3.x*a3.x + a3.y*a3.y + a3.z*a3.z + a3.w*a3.w;
        // reduce across the 16 lanes of this row (lanes are 16-aligned groups)
        s  += __shfl_xor(s, 1);  s  += __shfl_xor(s, 2);
        s  += __shfl_xor(s, 4);  s  += __shfl_xor(s, 8);
        s2 += __shfl_xor(s2, 1); s2 += __shfl_xor(s2, 2);
        s2 += __shfl_xor(s2, 4); s2 += __shfl_xor(s2, 8);
        float mean = s * (1.f / 256.f);
        float var  = s2 * (1.f / 256.f) - mean * mean;
        float rs = rsqrtf(var + 1e-5f);
        float4 g0a = ((const float4*)(g0 + cbase))[0];
        float4 g0b = ((const float4*)(g0 + cbase))[1];
        float4 g0c = ((const float4*)(g0 + cbase))[2];
        float4 g0d = ((const float4*)(g0 + cbase))[3];
        float4 b0a = ((const float4*)(b0 + cbase))[0];
        float4 b0b = ((const float4*)(b0 + cbase))[1];
        float4 b0c = ((const float4*)(b0 + cbase))[2];
        float4 b0d = ((const float4*)(b0 + cbase))[3];
        short8 y0, y1;
        y0[0] = f2bf((a0.x - mean) * rs * g0a.x + b0a.x);
        y0[1] = f2bf((a0.y - mean) * rs * g0a.y + b0a.y);
        y0[2] = f2bf((a0.z - mean) * rs * g0a.z + b0a.z);
        y0[3] = f2bf((a0.w - mean) * rs * g0a.w + b0a.w);
        y0[4] = f2bf((a1.x - mean) * rs * g0b.x + b0b.x);
        y0[5] = f2bf((a1.y - mean) * rs * g0b.y + b0b.y);
        y0[6] = f2bf((a1.z - mean) * rs * g0b.z + b0b.z);
        y0[7] = f2bf((a1.w - mean) * rs * g0b.w + b0b.w);
        y1[0] = f2bf((a2.x - mean) * rs * g0c.x + b0c.x);
        y1[1] = f2bf((a2.y - mean) * rs * g0c.y + b0c.y);
        y1[2] = f2bf((a2.z - mean) * rs * g0c.z + b0c.z);
        y1[3] = f2bf((a2.w - mean) * rs * g0c.w + b0c.w);
        y1[4] = f2bf((a3.x - mean) * rs * g0d.x + b0d.x);
        y1[5] = f2bf((a3.y - mean) * rs * g0d.y + b0d.y);
        y1[6] = f2bf((a3.z - mean) * rs * g0d.z + b0d.z);
        y1[7] = f2bf((a3.w - mean) * rs * g0d.w + b0d.w);
        *(short8*)(&Xs[lrow][cbase])     = y0;
        *(short8*)(&Xs[lrow][cbase + 8]) = y1;
    }
    __syncthreads();

    // ---- Phase 2: GEMM from LDS. Wave covers 16 rows x 64 cols. ----
    const int lane = tid & 63, wid = tid >> 6;
    const int m = lane & 15, quad = lane >> 4;
    const int c0 = wid * 64;

    f32x4 acc[4];
    #pragma unroll
    for (int t = 0; t < 4; t++) acc[t] = (f32x4){0.f, 0.f, 0.f, 0.f};

    for (int kk = 0; kk < 256; kk += 32) {
        short8 af = *(const short8*)(&Xs[m][kk + quad * 8]);
        #pragma unroll
        for (int t = 0; t < 4; t++) {
            short8 bf = *(const short8*)(WoT + (c0 + t * 16 + m) * 256 + kk + quad * 8);
            acc[t] = __builtin_amdgcn_mfma_f32_16x16x32_bf16(af, bf, acc[t], 0, 0, 0);
        }
    }

    // ---- Phase 3: y = x + relu(c + bo); LN1 stats over this col-quarter ----
    float s1[4] = {0.f, 0.f, 0.f, 0.f};
    float s2v[4] = {0.f, 0.f, 0.f, 0.f};
    #pragma unroll
    for (int t = 0; t < 4; t++) {
        int n = c0 + t * 16 + m;
        float bon = bo[n];
        #pragma unroll
        for (int reg = 0; reg < 4; reg++) {
            int r = quad * 4 + reg;
            float xv = bf2f(Xs[r][n]);
            float c = acc[t][reg] + bon;
            float yv = xv + (c > 0.f ? c : 0.f);
            acc[t][reg] = yv;                       // reuse acc as y storage
            s1[reg] += yv;
            s2v[reg] += yv * yv;
        }
    }
    #pragma unroll
    for (int reg = 0; reg < 4; reg++) {
        float a = s1[reg], bsum = s2v[reg];
        a += __shfl_xor(a, 1); a += __shfl_xor(a, 2); a += __shfl_xor(a, 4); a += __shfl_xor(a, 8);
        bsum += __shfl_xor(bsum, 1); bsum += __shfl_xor(bsum, 2); bsum += __shfl_xor(bsum, 4); bsum += __shfl_xor(bsum, 8);
        s1[reg] = a; s2v[reg] = bsum;
    }
    if (m == 0) {
        #pragma unroll
        for (int reg = 0; reg < 4; reg++) {
            st[wid][0][quad * 4 + reg] = s1[reg];
            st[wid][1][quad * 4 + reg] = s2v[reg];
        }
    }
    __syncthreads();
    #pragma unroll
    for (int reg = 0; reg < 4; reg++) {
        int r = quad * 4 + reg;
        float t1 = st[0][0][r] + st[1][0][r] + st[2][0][r] + st[3][0][r];
        float t2 = st[0][1][r] + st[1][1][r] + st[2][1][r] + st[3][1][r];
        float mean = t1 * (1.f / 256.f);
        float var  = t2 * (1.f / 256.f) - mean * mean;
        float rs = rsqrtf(var + 1e-5f);
        int token = r0 + r;
        #pragma unroll
        for (int t = 0; t < 4; t++) {
            int n = c0 + t * 16 + m;
            out[(size_t)token * 256 + n] = (acc[t][reg] - mean) * rs * g1[n] + b1[n];
        }
    }
}

extern "C" void kernel_launch(void* const* d_in, const int* in_sizes, int n_in,
                              void* d_out, int out_size, void* d_ws, size_t ws_size,
                              hipStream_t stream) {
    const float* Q   = (const float*)d_in[0];
    const float* K   = (const float*)d_in[1];
    const int* lengths = (const int*)d_in[2];
    const float* Wq  = (const float*)d_in[3];
    const float* bq  = (const float*)d_in[4];
    const float* Wk  = (const float*)d_in[5];
    const float* bk  = (const float*)d_in[6];
    const float* Wv  = (const float*)d_in[7];
    const float* bv  = (const float*)d_in[8];
    const float* Wo  = (const float*)d_in[9];
    const float* bo  = (const float*)d_in[10];
    const float* g0  = (const float*)d_in[11];
    const float* b0  = (const float*)d_in[12];
    const float* g1  = (const float*)d_in[13];
    const float* b1  = (const float*)d_in[14];
    float* out = (float*)d_out;

    char* ws = (char*)d_ws;
    short* qb  = (short*)(ws);                         // [8][8][1024][32] bf16, 4 MB
    short* kb  = (short*)(ws + (4u << 20));            // 4 MB (pre-scaled by 1/16)
    short* vT  = (short*)(ws + (8u << 20));            // [8][8][32][1024] bf16, 4 MB
    float* O1  = (float*)(ws + (12u << 20));           // [8192][256] f32, 8 MB
    short* WqT = (short*)(ws + (20u << 20));           // 128 KB each, [n][k] bf16
    short* WkT = (short*)(ws + (20u << 20) + (128u << 10));
    short* WvT = (short*)(ws + (20u << 20) + (256u << 10));
    short* WoT = (short*)(ws + (20u << 20) + (384u << 10));

    wtrans_kernel<<<dim3(16, 4), 256, 0, stream>>>(Wq, Wk, Wv, Wo, WqT, WkT, WvT, WoT);
    proj_kernel<<<dim3(256, 2), 256, 0, stream>>>(Q, K, WqT, WkT, WvT, bq, bk, bv,
                                                  lengths, qb, kb, vT);
    attn_kernel<<<dim3(16, 64), 256, 0, stream>>>(qb, kb, vT, lengths, O1);
    out_kernel<<<dim3(512), 256, 0, stream>>>(O1, WoT, g0, b0, bo, g1, b1, out);
}